// Round 3
// baseline (261.678 us; speedup 1.0000x reference)
//
#include <hip/hip_runtime.h>

// FFF tree-routing MLP, MI355X — fp32 I/O. Round 8: asm-forced load ILP.
//
// R7 post-mortem: VGPR=64 (= compiler's 8-waves/SIMD cap) and dur unchanged.
// Solving VALUBusy=11% + dur=240K cy gives ~2.7 waves/SIMD and ~6-7K cy per
// tree level = 8 serialized ~800cy L3 round-trips: the allocator recycles 4
// VGPRs for the 8 w-row float4 loads. Source-level batching hints failed 3
// rounds; this round forces 8-deep ILP with inline asm: 8 global_load_dwordx4
// with distinct "=v" outputs + one s_waitcnt vmcnt(0) that ties all 8 as
// "+v" (stops reg-only consumers hoisting past the wait — rule #18). Scores
// buffered in regs, stored once (keeps stores out of vmcnt(0)). Butterfly
// reduce unchanged (bit-identical; DPP would change the association tree).
// phaseB redesigned: 4 sibling leaves per block share levels 0-9 -> 16 rows
// for avg-16 tokens (6KB/token vs 24KB), staged in 64KB LDS per D_OUT-half,
// tokens register-blocked x8; 12 g-values expand to 16 slots (zero off-path
// slots add exactly +/-0 -> bit-identical, ascending-level order preserved).

#define D_IN    2048
#define D_OUT   2048
#define DEPTHP1 12
#define N_NODES 4095
#define N_TOK   8192
#define N_LEAF  2048

typedef float f4 __attribute__((ext_vector_type(4)));

// ---------------- K1: fused transpose (odd blocks) + phaseA (even blocks) --
__global__ __launch_bounds__(256, 4) void fusedA3(
    const float* __restrict__ x,       // [N_TOK, D_IN]
    const float* __restrict__ w_in,    // [N_NODES, D_IN]
    const float* __restrict__ w_out,   // [D_OUT, N_NODES]
    float* __restrict__ w_out_t,       // [N_NODES, D_OUT]
    float* __restrict__ s_all,         // [N_TOK, 12] RAW scores
    int* __restrict__ leaf,            // [N_TOK]
    int* __restrict__ hist) {          // [N_LEAF]
    if (blockIdx.x & 1) {
        // ---- transpose tile: w_out[j][n] -> w_out_t[n][j] ----
        __shared__ float tile[64][65];
        const int tb = blockIdx.x >> 1;
        const int n0 = (tb & 63) * 64;
        const int j0 = (tb >> 6) * 64;
        const int tx = threadIdx.x & 63;
        const int ty = threadIdx.x >> 6;
        const int n = n0 + tx;
#pragma unroll
        for (int k = 0; k < 16; k++) {
            const int r = ty * 16 + k;
            if (n < N_NODES) tile[r][tx] = w_out[(size_t)(j0 + r) * N_NODES + n];
        }
        __syncthreads();
#pragma unroll
        for (int k = 0; k < 16; k++) {
            const int r = ty * 16 + k;
            const int nn = n0 + r;
            if (nn < N_NODES) w_out_t[(size_t)nn * D_OUT + (j0 + tx)] = tile[tx][r];
        }
        return;
    }

    // ---- phaseA: tree descent, one wave per token, x in registers ----
    const int wave  = threadIdx.x >> 6;
    const int lane  = threadIdx.x & 63;
    const int token = (blockIdx.x >> 1) * 4 + wave;

    const float4* xrow = (const float4*)(x + (size_t)token * D_IN);
    float4 xf[8];
#pragma unroll
    for (int c = 0; c < 8; c++) xf[c] = xrow[lane + 64 * c];

    const unsigned voffA = (unsigned)lane * 16u;          // bytes
    const unsigned voffB = voffA + 4096u;                 // c=4..7 window

    int cur = 0;
    float sc[DEPTHP1];
#pragma unroll
    for (int l = 0; l < DEPTHP1; l++) {
        const float* wbase = w_in + (size_t)cur * D_IN;   // wave-uniform (SGPR)
        f4 w0, w1, w2, w3, w4, w5, w6, w7;
        // 8 loads issued back-to-back: ONE memory round-trip per level.
        asm volatile("global_load_dwordx4 %0, %1, %2"             : "=v"(w0) : "v"(voffA), "s"(wbase));
        asm volatile("global_load_dwordx4 %0, %1, %2 offset:1024" : "=v"(w1) : "v"(voffA), "s"(wbase));
        asm volatile("global_load_dwordx4 %0, %1, %2 offset:2048" : "=v"(w2) : "v"(voffA), "s"(wbase));
        asm volatile("global_load_dwordx4 %0, %1, %2 offset:3072" : "=v"(w3) : "v"(voffA), "s"(wbase));
        asm volatile("global_load_dwordx4 %0, %1, %2"             : "=v"(w4) : "v"(voffB), "s"(wbase));
        asm volatile("global_load_dwordx4 %0, %1, %2 offset:1024" : "=v"(w5) : "v"(voffB), "s"(wbase));
        asm volatile("global_load_dwordx4 %0, %1, %2 offset:2048" : "=v"(w6) : "v"(voffB), "s"(wbase));
        asm volatile("global_load_dwordx4 %0, %1, %2 offset:3072" : "=v"(w7) : "v"(voffB), "s"(wbase));
        // Tie all 8 results through the wait so consumers can't hoist past it.
        asm volatile("s_waitcnt vmcnt(0)"
                     : "+v"(w0), "+v"(w1), "+v"(w2), "+v"(w3),
                       "+v"(w4), "+v"(w5), "+v"(w6), "+v"(w7)
                     :: "memory");

        float p0 = 0.f, p1 = 0.f, p2 = 0.f, p3 = 0.f;
        p0 += w0[0]*xf[0].x + w0[1]*xf[0].y + w0[2]*xf[0].z + w0[3]*xf[0].w;
        p0 += w1[0]*xf[1].x + w1[1]*xf[1].y + w1[2]*xf[1].z + w1[3]*xf[1].w;
        p1 += w2[0]*xf[2].x + w2[1]*xf[2].y + w2[2]*xf[2].z + w2[3]*xf[2].w;
        p1 += w3[0]*xf[3].x + w3[1]*xf[3].y + w3[2]*xf[3].z + w3[3]*xf[3].w;
        p2 += w4[0]*xf[4].x + w4[1]*xf[4].y + w4[2]*xf[4].z + w4[3]*xf[4].w;
        p2 += w5[0]*xf[5].x + w5[1]*xf[5].y + w5[2]*xf[5].z + w5[3]*xf[5].w;
        p3 += w6[0]*xf[6].x + w6[1]*xf[6].y + w6[2]*xf[6].z + w6[3]*xf[6].w;
        p3 += w7[0]*xf[7].x + w7[1]*xf[7].y + w7[2]*xf[7].z + w7[3]*xf[7].w;
        float part = (p0 + p1) + (p2 + p3);
#pragma unroll
        for (int off = 32; off >= 1; off >>= 1)
            part += __shfl_xor(part, off, 64);
        const float score = part;                          // wave-uniform
        cur = __builtin_amdgcn_readfirstlane(
                  2 * cur + 1 + (score >= 0.f ? 1 : 0));   // SGPR for next base
        sc[l] = score;                                     // store at the end
    }
    if (lane == 0) {
        f4* sp = (f4*)(s_all + (size_t)token * DEPTHP1);
        f4 a = {sc[0], sc[1], sc[2],  sc[3]};
        f4 b = {sc[4], sc[5], sc[6],  sc[7]};
        f4 c = {sc[8], sc[9], sc[10], sc[11]};
        sp[0] = a; sp[1] = b; sp[2] = c;
        const int leafid = ((cur - 1) >> 1) - (N_LEAF - 1);
        leaf[token] = leafid;
        atomicAdd(&hist[leafid], 1);
    }
}

// ---------------- K2: zero hist + cnt (contiguous 2*N_LEAF ints) -----------
__global__ __launch_bounds__(256) void init_counts(int* __restrict__ p) {
    const int i = blockIdx.x * 256 + threadIdx.x;
    if (i < 2 * N_LEAF) p[i] = 0;
}

// ---------------- K3: exclusive scan over 2048 bins ------------------------
__global__ __launch_bounds__(256) void scan2048(
    const int* __restrict__ hist, int* __restrict__ offsets /*[2049]*/) {
    __shared__ int vals[N_LEAF];
    __shared__ int partial[256];
    const int t = threadIdx.x;
    int sum = 0;
#pragma unroll
    for (int k = 0; k < 8; k++) {
        const int v = hist[t * 8 + k];
        vals[t * 8 + k] = v;
        sum += v;
    }
    partial[t] = sum;
    __syncthreads();
    for (int off = 1; off < 256; off <<= 1) {
        const int v  = partial[t];
        const int vo = (t >= off) ? partial[t - off] : 0;
        __syncthreads();
        partial[t] = v + vo;
        __syncthreads();
    }
    int base = (t > 0) ? partial[t - 1] : 0;
#pragma unroll
    for (int k = 0; k < 8; k++) {
        offsets[t * 8 + k] = base;
        base += vals[t * 8 + k];
    }
    if (t == 255) offsets[N_LEAF] = base;  // == N_TOK
}

// ---------------- K4: scatter tokens; apply gelu HERE ----------------------
__global__ __launch_bounds__(256) void scatter_tokens3(
    const int* __restrict__ leaf, const int* __restrict__ offsets,
    int* __restrict__ cnt, const float* __restrict__ s_all,
    int* __restrict__ order, float* __restrict__ g_sorted,
    int* __restrict__ lf_sorted) {
    const int t = blockIdx.x * 256 + threadIdx.x;
    if (t < N_TOK) {
        const int lf = leaf[t];
        const int pos = offsets[lf] + atomicAdd(&cnt[lf], 1);
        order[pos] = t;
        lf_sorted[pos] = lf;
#pragma unroll
        for (int l = 0; l < DEPTHP1; l++) {
            const float s = s_all[(size_t)t * DEPTHP1 + l];
            const float g = 0.5f * s * (1.0f + erff(s * 0.70710678118654752f));
            g_sorted[(size_t)pos * DEPTHP1 + l] = g;
        }
    }
}

// ---------------- K5: phase B — 4-leaf groups, LDS-staged rows -------------
__global__ __launch_bounds__(256, 2) void phaseB4(
    const float* __restrict__ w_out_t,   // [N_NODES, D_OUT]
    const float* __restrict__ g_sorted,  // [N_TOK, 12] leaf-sorted, gelu'd
    const int* __restrict__ lf_sorted,   // [N_TOK]
    const int* __restrict__ order,       // [N_TOK]
    const int* __restrict__ offsets,     // [N_LEAF+1]
    float* __restrict__ out) {           // [N_TOK, D_OUT]
    // 512 groups of 4 sibling leaves; XCD swizzle (512 = 8*64, bijective).
    const int grp = ((blockIdx.x & 7) << 6) | (blockIdx.x >> 3);
    const int lf0 = grp * 4;
    const int start = offsets[lf0];
    const int end   = offsets[lf0 + 4];
    if (start == end) return;
    const int t = threadIdx.x;            // owns float4 col t of current half

    __shared__ float wlds[16 * 1024];     // 16 rows x half-D_OUT = 64 KB
    __shared__ float gslot[2][8][16];     // double-buffered slot vectors
    __shared__ int   ordl[2][8];

    // 16 distinct w_out_t rows: levels 0-9 shared, 2 @ level 10, 4 @ level 11.
    int node[16];
    const int base1 = lf0 + N_LEAF;       // heap id of leaf lf0 (even, %4==0)
#pragma unroll
    for (int l = 0; l <= 9; l++) node[l] = (base1 >> (11 - l)) - 1;
    node[10] = (base1 >> 1) - 1;          // level-10, leaf pair 0
    node[11] = (base1 >> 1);              // level-10, leaf pair 1
    node[12] = base1 - 1;                 // level-11 leaves
    node[13] = base1;
    node[14] = base1 + 1;
    node[15] = base1 + 2;

    for (int half = 0; half < 2; half++) {
        __syncthreads();                  // prior-half readers done
#pragma unroll
        for (int k = 0; k < 16; k++)      // stage row k, cols [half*1024, +1024)
            ((f4*)wlds)[k * 256 + t] =
                ((const f4*)(w_out_t + (size_t)node[k] * D_OUT + half * 1024))[t];
        __syncthreads();

        int buf = 0;
        for (int cs = start; cs < end; cs += 8, buf ^= 1) {
            if (t < 8) {
                const int pos = cs + t;
#pragma unroll
                for (int s = 0; s < 16; s++) gslot[buf][t][s] = 0.f;
                if (pos < end) {
                    const int lf = lf_sorted[pos];
#pragma unroll
                    for (int l = 0; l <= 9; l++)
                        gslot[buf][t][l] = g_sorted[(size_t)pos * DEPTHP1 + l];
                    gslot[buf][t][10 + ((lf >> 1) & 1)] =
                        g_sorted[(size_t)pos * DEPTHP1 + 10];
                    gslot[buf][t][12 + (lf & 3)] =
                        g_sorted[(size_t)pos * DEPTHP1 + 11];
                    ordl[buf][t] = order[pos];
                }
            }
            __syncthreads();              // double-buffer: 1 barrier per chunk
            const int T = end - cs;       // tokens this chunk: min(T,8)
            f4 acc[8];
#pragma unroll
            for (int tt = 0; tt < 8; tt++) acc[tt] = (f4)0.f;
#pragma unroll
            for (int r = 0; r < 16; r++) {  // ascending level order preserved
                const f4 w = ((const f4*)wlds)[r * 256 + t];
#pragma unroll
                for (int tt = 0; tt < 8; tt++) {
                    const float g = gslot[buf][tt][r];   // broadcast read
                    acc[tt] += g * w;                    // zero slots: +/-0 no-op
                }
            }
#pragma unroll
            for (int tt = 0; tt < 8; tt++) {
                if (tt < T) {
                    const int tok = ordl[buf][tt];
                    ((f4*)(out + (size_t)tok * D_OUT + half * 1024))[t] = acc[tt];
                }
            }
        }
    }
}

// ---------------- Fallback kernels (small workspace) -----------------------
__global__ __launch_bounds__(256) void transpose_wout64(
    const float* __restrict__ in, float* __restrict__ out) {
    __shared__ float tile[64][65];
    const int n0 = blockIdx.x * 64;
    const int j0 = blockIdx.y * 64;
    const int tx = threadIdx.x;
    const int ty = threadIdx.y;
    const int n = n0 + tx;
#pragma unroll
    for (int k = 0; k < 16; k++) {
        const int r = ty * 16 + k;
        if (n < N_NODES) tile[r][tx] = in[(size_t)(j0 + r) * N_NODES + n];
    }
    __syncthreads();
#pragma unroll
    for (int k = 0; k < 16; k++) {
        const int r = ty * 16 + k;
        const int nn = n0 + r;
        if (nn < N_NODES) out[(size_t)nn * D_OUT + (j0 + tx)] = tile[tx][r];
    }
}

template <bool TRANSPOSED>
__global__ __launch_bounds__(256) void fff_fused(
    const float* __restrict__ x, const float* __restrict__ w_in,
    const float* __restrict__ w_out, float* __restrict__ out) {
    const int wave  = threadIdx.x >> 6;
    const int lane  = threadIdx.x & 63;
    const int token = blockIdx.x * 4 + wave;
    const float4* xrow = (const float4*)(x + (size_t)token * D_IN);
    float xf[32];
#pragma unroll
    for (int c = 0; c < 8; c++) {
        float4 xc = xrow[lane + 64 * c];
        xf[c * 4 + 0] = xc.x; xf[c * 4 + 1] = xc.y;
        xf[c * 4 + 2] = xc.z; xf[c * 4 + 3] = xc.w;
    }
    float acc[32];
#pragma unroll
    for (int k = 0; k < 32; k++) acc[k] = 0.f;
    int cur = 0;
#pragma unroll
    for (int l = 0; l < DEPTHP1; l++) {
        const float4* wrow = (const float4*)(w_in + (size_t)cur * D_IN);
        float part = 0.f;
#pragma unroll
        for (int c = 0; c < 8; c++) {
            float4 wc = wrow[lane + 64 * c];
            part += wc.x * xf[c * 4 + 0]; part += wc.y * xf[c * 4 + 1];
            part += wc.z * xf[c * 4 + 2]; part += wc.w * xf[c * 4 + 3];
        }
#pragma unroll
        for (int off = 32; off >= 1; off >>= 1) part += __shfl_xor(part, off, 64);
        const float score = part;
        const float g = 0.5f * score * (1.0f + erff(score * 0.70710678118654752f));
        if (TRANSPOSED) {
            const float4* orow = (const float4*)(w_out + (size_t)cur * D_OUT);
#pragma unroll
            for (int c = 0; c < 8; c++) {
                float4 oc = orow[lane + 64 * c];
                acc[c * 4 + 0] += g * oc.x; acc[c * 4 + 1] += g * oc.y;
                acc[c * 4 + 2] += g * oc.z; acc[c * 4 + 3] += g * oc.w;
            }
        } else {
#pragma unroll
            for (int c = 0; c < 8; c++)
#pragma unroll
                for (int k = 0; k < 4; k++) {
                    const int j = (lane + 64 * c) * 4 + k;
                    acc[c * 4 + k] += g * w_out[(size_t)j * N_NODES + cur];
                }
        }
        cur = 2 * cur + 1 + (score >= 0.f ? 1 : 0);
    }
    float4* outrow = (float4*)(out + (size_t)token * D_OUT);
#pragma unroll
    for (int c = 0; c < 8; c++) {
        float4 o;
        o.x = acc[c * 4 + 0]; o.y = acc[c * 4 + 1];
        o.z = acc[c * 4 + 2]; o.w = acc[c * 4 + 3];
        outrow[lane + 64 * c] = o;
    }
}

extern "C" void kernel_launch(void* const* d_in, const int* in_sizes, int n_in,
                              void* d_out, int out_size, void* d_ws, size_t ws_size,
                              hipStream_t stream) {
    (void)in_sizes; (void)n_in; (void)out_size;
    const float* x     = (const float*)d_in[0];
    const float* w_in  = (const float*)d_in[1];
    const float* w_out = (const float*)d_in[2];
    float* out = (float*)d_out;

    const size_t wt_bytes   = (size_t)N_NODES * D_OUT * sizeof(float);   // 33.546 MB
    const size_t g_bytes    = (size_t)N_TOK * DEPTHP1 * sizeof(float);   // 393 KB
    const size_t leaf_bytes = (size_t)N_TOK * sizeof(int);
    const size_t ord_bytes  = (size_t)N_TOK * sizeof(int);
    const size_t hist_bytes = (size_t)N_LEAF * sizeof(int);
    const size_t cnt_bytes  = (size_t)N_LEAF * sizeof(int);
    const size_t offs_bytes = (size_t)(N_LEAF + 1) * sizeof(int);
    const size_t gs_bytes   = g_bytes;                                   // g_sorted
    const size_t lfs_bytes  = (size_t)N_TOK * sizeof(int);               // lf_sorted
    const size_t need = wt_bytes + g_bytes + leaf_bytes + ord_bytes +
                        hist_bytes + cnt_bytes + offs_bytes + gs_bytes +
                        lfs_bytes + 64;

    if (ws_size >= need) {
        char* p = (char*)d_ws;
        float* w_out_t  = (float*)p;  p += wt_bytes;
        float* s_all    = (float*)p;  p += g_bytes;
        int*   leaf     = (int*)p;    p += leaf_bytes;
        int*   order    = (int*)p;    p += ord_bytes;
        int*   hist     = (int*)p;    p += hist_bytes;   // hist+cnt contiguous
        int*   cnt      = (int*)p;    p += cnt_bytes;
        int*   offsets  = (int*)p;    p += offs_bytes;
        float* g_sorted = (float*)p;  p += gs_bytes;
        int*   lf_sorted= (int*)p;

        init_counts<<<(2 * N_LEAF + 255) / 256, 256, 0, stream>>>(hist);
        // Even blocks: phaseA (2048 token-quads). Odd blocks: transpose tiles.
        fusedA3<<<4096, 256, 0, stream>>>(x, w_in, w_out, w_out_t,
                                          s_all, leaf, hist);
        scan2048<<<1, 256, 0, stream>>>(hist, offsets);
        scatter_tokens3<<<N_TOK / 256, 256, 0, stream>>>(leaf, offsets, cnt,
                                                         s_all, order, g_sorted,
                                                         lf_sorted);
        phaseB4<<<512, 256, 0, stream>>>(w_out_t, g_sorted, lf_sorted, order,
                                         offsets, out);
    } else if (ws_size >= wt_bytes) {
        float* w_out_t = (float*)d_ws;
        transpose_wout64<<<dim3((N_NODES + 63) / 64, D_OUT / 64), dim3(64, 4),
                           0, stream>>>(w_out, w_out_t);
        fff_fused<true><<<N_TOK / 4, 256, 0, stream>>>(x, w_in, w_out_t, out);
    } else {
        fff_fused<false><<<N_TOK / 4, 256, 0, stream>>>(x, w_in, w_out, out);
    }
}